// Round 10
// baseline (80.151 us; speedup 1.0000x reference)
//
#include <hip/hip_runtime.h>
#include <hip/hip_bf16.h>

#define BATCH 32
#define NNODE 2048
#define NEDGE 8192
#define DIM   512
#define NREL  8
#define VG    50000
#define VS    25000
#define ZI    4608           // 512 (root) + 8*512 (basis)
#define NCH   36             // 4608 / 128 i-chunks
#define NT_G  3125           // 50000/16 global-head tiles
#define TTOT  4688           // total 16-row tiles
#define NW9   2344           // waves; each handles tiles w and w+2344
#define ROWB  1040           // LDS row stride: 1KB + 16B pad
#define BUFB  16640          // 16 * 1040

typedef __attribute__((ext_vector_type(4))) float f32x4;
typedef __attribute__((ext_vector_type(8))) short s16x8;

// ---------------------------------------------------------------------------
// K1: per-batch edge scan (dst==0 only), builds z[g][0..4607]
// ---------------------------------------------------------------------------
__global__ __launch_bounds__(512) void k_conv(const float* __restrict__ x,
                                              const int* __restrict__ ei,
                                              const int* __restrict__ et,
                                              const float* __restrict__ comp,
                                              float* __restrict__ z) {
    int g = blockIdx.x;
    int t = threadIdx.x;
    int wv = t >> 6, lane = t & 63;
    __shared__ int elds[8 * 128];
    __shared__ int wcnt[8];
    const int* srcp = ei + (size_t)(g * 2 + 0) * NEDGE;
    const int* dstp = ei + (size_t)(g * 2 + 1) * NEDGE;

    int run = 0;
    for (int it = 0; it < 16; it++) {
        int e = wv * 1024 + it * 64 + lane;
        bool m = (dstp[e] == 0);
        unsigned long long mask = __ballot(m);
        int rank = __popcll(mask & ((1ull << lane) - 1ull));
        if (m && (run + rank) < 128) elds[wv * 128 + run + rank] = e;
        run += (int)__popcll(mask);
    }
    if (lane == 0) wcnt[wv] = (run > 128) ? 128 : run;
    __syncthreads();

    int d = t;
    float s0=0,s1=0,s2=0,s3=0,s4=0,s5=0,s6=0,s7=0;
    int   c0=0,c1=0,c2=0,c3=0,c4=0,c5=0,c6=0,c7=0;
    for (int w = 0; w < 8; w++) {
        int cw = wcnt[w];
        for (int i = 0; i < cw; i++) {
            int e = elds[w * 128 + i];
            int r = et[(size_t)g * NEDGE + e];
            int sn = srcp[e];
            float val = x[((size_t)g * NNODE + sn) * DIM + d];
            if (r == 0) { s0 += val; c0++; }
            if (r == 1) { s1 += val; c1++; }
            if (r == 2) { s2 += val; c2++; }
            if (r == 3) { s3 += val; c3++; }
            if (r == 4) { s4 += val; c4++; }
            if (r == 5) { s5 += val; c5++; }
            if (r == 6) { s6 += val; c6++; }
            if (r == 7) { s7 += val; c7++; }
        }
    }
    float sv[8] = {s0,s1,s2,s3,s4,s5,s6,s7};
    float inv[8];
    int   cv[8] = {c0,c1,c2,c3,c4,c5,c6,c7};
    #pragma unroll
    for (int r = 0; r < 8; r++) inv[r] = 1.0f / fmaxf((float)cv[r], 1.0f);

    z[(size_t)g * ZI + d] = x[((size_t)g * NNODE + 0) * DIM + d];
    #pragma unroll
    for (int b = 0; b < 8; b++) {
        float y = 0.f;
        #pragma unroll
        for (int r = 0; r < 8; r++) y += comp[r * 8 + b] * inv[r] * sv[r];
        z[(size_t)g * ZI + 512 + b * 512 + d] = y;
    }
}

// ---------------------------------------------------------------------------
// K2a: partial GEMM  part2[c][g][d] = sum_{i in chunk c} z[g][i] * M[i][d]
// ---------------------------------------------------------------------------
__global__ __launch_bounds__(512) void k_gemm_part(const float* __restrict__ z,
                                                   const float* __restrict__ root,
                                                   const float* __restrict__ basis,
                                                   float* __restrict__ part2) {
    int bx = blockIdx.x;
    int dt = bx & 3;
    int cc = bx >> 2;
    int t = threadIdx.x;
    int dl = t & 127, gq = t >> 7;
    __shared__ float ztT[128][33];
    #pragma unroll
    for (int rep = 0; rep < 8; rep++) {
        int flat = rep * 512 + t;
        int g = flat >> 7, i = flat & 127;
        ztT[i][g] = z[(size_t)g * ZI + cc * 128 + i];
    }
    __syncthreads();
    const float* M = (cc < 4) ? (root + (size_t)(cc * 128) * 512)
                              : (basis + (size_t)((cc - 4) * 128) * 512);
    float acc[8] = {0,0,0,0,0,0,0,0};
    for (int i = 0; i < 128; i++) {
        float m = M[(size_t)i * 512 + dt * 128 + dl];
        #pragma unroll
        for (int j = 0; j < 8; j++) acc[j] += ztT[i][gq * 8 + j] * m;
    }
    #pragma unroll
    for (int j = 0; j < 8; j++) {
        int g = gq * 8 + j;
        part2[((size_t)cc * 32 + g) * 512 + dt * 128 + dl] = acc[j];
    }
}

// ---------------------------------------------------------------------------
// K2b: h0 reduce + relu + pack bf16 pairs.  h0t[g*256 + p] = bf16(2p)|bf16(2p+1)<<16
// ---------------------------------------------------------------------------
__device__ __forceinline__ unsigned bf16rne(float f) {
    unsigned u = __float_as_uint(f);
    return (u + 0x7FFFu + ((u >> 16) & 1u)) >> 16;
}

__global__ __launch_bounds__(256) void k_h0(const float* __restrict__ part2,
                                            const float* __restrict__ bias_conv,
                                            unsigned* __restrict__ h0t) {
    int g = blockIdx.x;
    int p = threadIdx.x;
    int d0 = 2 * p;
    float v0 = bias_conv[d0], v1 = bias_conv[d0 + 1];
    for (int cc = 0; cc < NCH; cc++) {
        const float* pp = part2 + ((size_t)cc * 32 + g) * 512 + d0;
        v0 += pp[0];
        v1 += pp[1];
    }
    v0 = fmaxf(v0, 0.f);
    v1 = fmaxf(v1, 0.f);
    h0t[g * 256 + p] = bf16rne(v0) | (bf16rne(v1) << 16);
}

// ---------------------------------------------------------------------------
// K3 v9: contiguous-DMA, full-duty, barrier-free streaming MFMA GEMV.
// One wave per 64-thread block; wave w handles tiles w and w+2344 (16 vocab
// rows x K=512 each). W streamed via global_load_lds: every instruction a
// fully contiguous lane-ascending 1KB half-K row -> m13-class access pattern.
// Per-wave private double buffer (2 x 16 rows x 1040B), counted vmcnt waits
// (16/16/16/0), NO __syncthreads anywhere, no WG churn mid-stream.
// MFMA roles swapped: A = W (from LDS, fp32->bf16), B = h0 fragments held in
// 128 VGPRs (loaded once from L2-hot h0t). D: row=(l>>4)*4+j -> vocab,
// col=l&15 -> batch. Fused exp-partials per tile -> part[tile*32+g].
// ---------------------------------------------------------------------------
__device__ __forceinline__ void gload_lds16(const float* gsrc, float* ldst) {
    __builtin_amdgcn_global_load_lds(
        (const __attribute__((address_space(1))) void*)gsrc,
        (__attribute__((address_space(3))) void*)ldst,
        16, 0, 0);
}

__device__ __forceinline__ short f2bf(float f) {
    __hip_bfloat16 h = __float2bfloat16(f);
    return *reinterpret_cast<short*>(&h);
}

#define VMWAIT(n) asm volatile("s_waitcnt vmcnt(" #n ")" ::: "memory")
#define MEMFENCE() asm volatile("" ::: "memory")

__global__ __launch_bounds__(64) void k_logits9(const unsigned* __restrict__ h0t,
                                                const float* __restrict__ wg,
                                                const float* __restrict__ bg,
                                                const float* __restrict__ wsn,
                                                const float* __restrict__ bsv,
                                                float* __restrict__ out,
                                                float* __restrict__ part) {
    __shared__ __align__(16) unsigned char wlds[2 * BUFB];   // 33280B

    int l = threadIdx.x;
    int w = blockIdx.x;            // wave id 0..2343
    int t0 = w, t1 = w + NW9;

    // ---- tile parameter resolve ----
    const float *w0p, *b0p, *w1p, *b1p;
    float *o0p, *o1p;
    int V0, V1, v00, v01;
    if (t0 < NT_G) { w0p = wg;  b0p = bg;  o0p = out;                      V0 = VG; v00 = t0 * 16; }
    else           { w0p = wsn; b0p = bsv; o0p = out + (size_t)BATCH * VG; V0 = VS; v00 = (t0 - NT_G) * 16; }
    if (t1 < NT_G) { w1p = wg;  b1p = bg;  o1p = out;                      V1 = VG; v01 = t1 * 16; }
    else           { w1p = wsn; b1p = bsv; o1p = out + (size_t)BATCH * VG; V1 = VS; v01 = (t1 - NT_G) * 16; }

    // ---- prologue register loads: bias (8) + h0 fragments (32) ----
    int vrow = (l >> 4) * 4;       // this lane's first vocab row within tile
    float bA[4], bB[4];
    #pragma unroll
    for (int j = 0; j < 4; j++) {
        int va = v00 + vrow + j;  bA[j] = b0p[va < V0 ? va : V0 - 1];
        int vb = v01 + vrow + j;  bB[j] = b1p[vb < V1 ? vb : V1 - 1];
    }
    s16x8 h0f[16][2];
    {
        const unsigned char* hbase = (const unsigned char*)h0t;
        int hoff = (l & 15) * 1024 + (l >> 4) * 16;
        #pragma unroll
        for (int kc = 0; kc < 16; kc++) {
            h0f[kc][0] = *(const s16x8*)(hbase + hoff + kc * 64);
            h0f[kc][1] = *(const s16x8*)(hbase + 16384 + hoff + kc * 64);
        }
    }
    MEMFENCE();   // pin all register loads BEFORE the DMA issues (exact vmcnt counts)

    // ---- DMA issue helper: 16 contiguous 1KB loads (one per row, half-K KH) ----
#define ISSUE(WP, V0_, VLIM, BUF, KH) do {                                    \
        _Pragma("unroll")                                                     \
        for (int r = 0; r < 16; r++) {                                        \
            int vr = (V0_) + r; if (vr > (VLIM) - 1) vr = (VLIM) - 1;         \
            const float* srcp = (WP) + (size_t)vr * 512 + (KH) * 256 + l * 4; \
            gload_lds16(srcp, (float*)&wlds[(BUF) * BUFB + r * ROWB]);        \
        }                                                                     \
    } while (0)

#define COMPUTE(KH, BUF, A0, A1) do {                                         \
        const unsigned char* wbp = wlds + (BUF) * BUFB + (l & 15) * ROWB      \
                                   + ((l >> 4) * 32);                         \
        _Pragma("unroll")                                                     \
        for (int kcl = 0; kcl < 8; kcl++) {                                   \
            f32x4 wlo = *(const f32x4*)(wbp + kcl * 128);                     \
            f32x4 whi = *(const f32x4*)(wbp + kcl * 128 + 16);                \
            s16x8 a;                                                          \
            a[0] = f2bf(wlo[0]); a[1] = f2bf(wlo[1]);                         \
            a[2] = f2bf(wlo[2]); a[3] = f2bf(wlo[3]);                         \
            a[4] = f2bf(whi[0]); a[5] = f2bf(whi[1]);                         \
            a[6] = f2bf(whi[2]); a[7] = f2bf(whi[3]);                         \
            A0 = __builtin_amdgcn_mfma_f32_16x16x32_bf16(a, h0f[(KH)*8+kcl][0], A0, 0, 0, 0); \
            A1 = __builtin_amdgcn_mfma_f32_16x16x32_bf16(a, h0f[(KH)*8+kcl][1], A1, 0, 0, 0); \
        }                                                                     \
    } while (0)

#define STORE(TIL, OP, VLIM, V0_, BP4, A0, A1) do {                           \
        float s0 = 0.f, s1 = 0.f;                                             \
        _Pragma("unroll")                                                     \
        for (int j = 0; j < 4; j++) {                                         \
            int v = (V0_) + vrow + j;                                         \
            float L0 = A0[j] + BP4[j];                                        \
            float L1 = A1[j] + BP4[j];                                        \
            if (v < (VLIM)) {                                                 \
                (OP)[(size_t)(l & 15) * (VLIM) + v]        = L0;              \
                (OP)[(size_t)(16 + (l & 15)) * (VLIM) + v] = L1;              \
                s0 += __expf(L0);                                             \
                s1 += __expf(L1);                                             \
            }                                                                 \
        }                                                                     \
        s0 += __shfl_xor(s0, 16); s0 += __shfl_xor(s0, 32);                   \
        s1 += __shfl_xor(s1, 16); s1 += __shfl_xor(s1, 32);                   \
        if (l < 16) {                                                         \
            part[(size_t)(TIL) * 32 + l]      = s0;                           \
            part[(size_t)(TIL) * 32 + 16 + l] = s1;                           \
        }                                                                     \
    } while (0)

    f32x4 accA0 = {0.f,0.f,0.f,0.f}, accA1 = {0.f,0.f,0.f,0.f};
    f32x4 accB0 = {0.f,0.f,0.f,0.f}, accB1 = {0.f,0.f,0.f,0.f};

    ISSUE(w0p, v00, V0, 0, 0);     // T0 k-half 0 -> buf0   (16 in flight)
    ISSUE(w0p, v00, V0, 1, 1);     // T0 k-half 1 -> buf1   (32)

    VMWAIT(16);                    // buf0 ready (h0/bias older, also done)
    COMPUTE(0, 0, accA0, accA1);
    ISSUE(w1p, v01, V1, 0, 0);     // T1 k-half 0 -> buf0   (buf1 + 16)

    VMWAIT(16);                    // buf1 (T0) ready
    COMPUTE(1, 1, accA0, accA1);
    ISSUE(w1p, v01, V1, 1, 1);     // T1 k-half 1 -> buf1   (32 in flight)

    VMWAIT(16);                    // buf0 (T1) ready
    STORE(t0, o0p, V0, v00, bA, accA0, accA1);
    COMPUTE(0, 0, accB0, accB1);

    VMWAIT(0);                     // buf1 (T1) ready (stores long done)
    COMPUTE(1, 1, accB0, accB1);
    STORE(t1, o1p, V1, v01, bB, accB0, accB1);

#undef ISSUE
#undef COMPUTE
#undef STORE
}

// ---------------------------------------------------------------------------
// K4a: lse[row] = log(sum over tiles of part[tile*32+g]); row = head*32+g
// ---------------------------------------------------------------------------
__global__ __launch_bounds__(256) void k_lse64(const float* __restrict__ part,
                                               float* __restrict__ lse) {
    int bx = blockIdx.x;           // 0..63
    int head = bx >> 5, g = bx & 31;
    int tbase = head ? NT_G : 0;
    int ntl   = head ? (TTOT - NT_G) : NT_G;
    int t = threadIdx.x;
    float s = 0.f;
    for (int i = t; i < ntl; i += 256)
        s += part[(size_t)(tbase + i) * 32 + g];
    #pragma unroll
    for (int m = 1; m < 64; m <<= 1) s += __shfl_xor(s, m);
    __shared__ float ws4[4];
    if ((t & 63) == 0) ws4[t >> 6] = s;
    __syncthreads();
    if (t == 0) lse[bx] = logf(ws4[0] + ws4[1] + ws4[2] + ws4[3]);
}

// ---------------------------------------------------------------------------
// K4b: out -= lse (broadcast per row)
// ---------------------------------------------------------------------------
__global__ __launch_bounds__(256) void k_sub(float* __restrict__ out,
                                             const float* __restrict__ lse) {
    unsigned i4 = blockIdx.x * 256u + threadIdx.x;
    if (i4 >= 600000u) return;
    unsigned idx = i4 * 4u;
    float l;
    if (idx < 1600000u) l = lse[idx / 50000u];
    else                l = lse[32u + (idx - 1600000u) / 25000u];
    float4 v = *(float4*)(out + idx);
    v.x -= l; v.y -= l; v.z -= l; v.w -= l;
    *(float4*)(out + idx) = v;
}

// ---------------------------------------------------------------------------
extern "C" void kernel_launch(void* const* d_in, const int* in_sizes, int n_in,
                              void* d_out, int out_size, void* d_ws, size_t ws_size,
                              hipStream_t stream) {
    const float* x        = (const float*)d_in[0];
    const int*   ei       = (const int*)  d_in[1];
    const int*   et       = (const int*)  d_in[2];
    const float* basis    = (const float*)d_in[3];
    const float* comp     = (const float*)d_in[4];
    const float* root     = (const float*)d_in[5];
    const float* biasc    = (const float*)d_in[6];
    const float* wg       = (const float*)d_in[7];
    const float* bg       = (const float*)d_in[8];
    const float* wsn      = (const float*)d_in[9];
    const float* bsv      = (const float*)d_in[10];
    float* out = (float*)d_out;

    float* z     = out;
    float* part2 = out + (size_t)BATCH * ZI;
    unsigned* h0t  = (unsigned*)d_ws;            // 8192 uints = 32KB
    float*    part = (float*)d_ws + 8192;        // 4688*32 floats = 600KB
    float*    lse  = part + (size_t)TTOT * 32;   // 64 floats

    k_conv     <<<BATCH, 512, 0, stream>>>(x, ei, et, comp, z);
    k_gemm_part<<<NCH * 4, 512, 0, stream>>>(z, root, basis, part2);
    k_h0       <<<BATCH, 256, 0, stream>>>(part2, biasc, h0t);
    k_logits9  <<<NW9, 64, 0, stream>>>(h0t, wg, bg, wsn, bsv, out, part);
    k_lse64    <<<64, 256, 0, stream>>>(part, lse);
    k_sub      <<<2344, 256, 0, stream>>>(out, lse);
}

// Round 11
// 73.725 us; speedup vs baseline: 1.0872x; 1.0872x over previous
//
#include <hip/hip_runtime.h>
#include <hip/hip_bf16.h>

#define BATCH 32
#define NNODE 2048
#define NEDGE 8192
#define DIM   512
#define NREL  8
#define VG    50000
#define VS    25000
#define ZI    4608           // 512 (root) + 8*512 (basis)
#define NCH   36             // 4608 / 128 i-chunks
#define NT_G  3125           // 50000/16 global-head wave-tiles
#define TTOT  4688           // total 16-row wave-tiles
#define NBLKA 586            // 586 blocks x 8 waves = 4688 wave-tiles

typedef __attribute__((ext_vector_type(4))) float f32x4;
typedef __attribute__((ext_vector_type(8))) short s16x8;

// ---------------------------------------------------------------------------
// K1: per-batch edge scan (dst==0 only), builds z[g][0..4607]
// ---------------------------------------------------------------------------
__global__ __launch_bounds__(512) void k_conv(const float* __restrict__ x,
                                              const int* __restrict__ ei,
                                              const int* __restrict__ et,
                                              const float* __restrict__ comp,
                                              float* __restrict__ z) {
    int g = blockIdx.x;
    int t = threadIdx.x;
    int wv = t >> 6, lane = t & 63;
    __shared__ int elds[8 * 128];
    __shared__ int wcnt[8];
    const int* srcp = ei + (size_t)(g * 2 + 0) * NEDGE;
    const int* dstp = ei + (size_t)(g * 2 + 1) * NEDGE;

    int run = 0;
    for (int it = 0; it < 16; it++) {
        int e = wv * 1024 + it * 64 + lane;
        bool m = (dstp[e] == 0);
        unsigned long long mask = __ballot(m);
        int rank = __popcll(mask & ((1ull << lane) - 1ull));
        if (m && (run + rank) < 128) elds[wv * 128 + run + rank] = e;
        run += (int)__popcll(mask);
    }
    if (lane == 0) wcnt[wv] = (run > 128) ? 128 : run;
    __syncthreads();

    int d = t;
    float s0=0,s1=0,s2=0,s3=0,s4=0,s5=0,s6=0,s7=0;
    int   c0=0,c1=0,c2=0,c3=0,c4=0,c5=0,c6=0,c7=0;
    for (int w = 0; w < 8; w++) {
        int cw = wcnt[w];
        for (int i = 0; i < cw; i++) {
            int e = elds[w * 128 + i];
            int r = et[(size_t)g * NEDGE + e];
            int sn = srcp[e];
            float val = x[((size_t)g * NNODE + sn) * DIM + d];
            if (r == 0) { s0 += val; c0++; }
            if (r == 1) { s1 += val; c1++; }
            if (r == 2) { s2 += val; c2++; }
            if (r == 3) { s3 += val; c3++; }
            if (r == 4) { s4 += val; c4++; }
            if (r == 5) { s5 += val; c5++; }
            if (r == 6) { s6 += val; c6++; }
            if (r == 7) { s7 += val; c7++; }
        }
    }
    float sv[8] = {s0,s1,s2,s3,s4,s5,s6,s7};
    float inv[8];
    int   cv[8] = {c0,c1,c2,c3,c4,c5,c6,c7};
    #pragma unroll
    for (int r = 0; r < 8; r++) inv[r] = 1.0f / fmaxf((float)cv[r], 1.0f);

    z[(size_t)g * ZI + d] = x[((size_t)g * NNODE + 0) * DIM + d];
    #pragma unroll
    for (int b = 0; b < 8; b++) {
        float y = 0.f;
        #pragma unroll
        for (int r = 0; r < 8; r++) y += comp[r * 8 + b] * inv[r] * sv[r];
        z[(size_t)g * ZI + 512 + b * 512 + d] = y;
    }
}

// ---------------------------------------------------------------------------
// K2a: partial GEMM  part2[c][g][d] = sum_{i in chunk c} z[g][i] * M[i][d]
// ---------------------------------------------------------------------------
__global__ __launch_bounds__(512) void k_gemm_part(const float* __restrict__ z,
                                                   const float* __restrict__ root,
                                                   const float* __restrict__ basis,
                                                   float* __restrict__ part2) {
    int bx = blockIdx.x;
    int dt = bx & 3;
    int cc = bx >> 2;
    int t = threadIdx.x;
    int dl = t & 127, gq = t >> 7;
    __shared__ float ztT[128][33];
    #pragma unroll
    for (int rep = 0; rep < 8; rep++) {
        int flat = rep * 512 + t;
        int g = flat >> 7, i = flat & 127;
        ztT[i][g] = z[(size_t)g * ZI + cc * 128 + i];
    }
    __syncthreads();
    const float* M = (cc < 4) ? (root + (size_t)(cc * 128) * 512)
                              : (basis + (size_t)((cc - 4) * 128) * 512);
    float acc[8] = {0,0,0,0,0,0,0,0};
    for (int i = 0; i < 128; i++) {
        float m = M[(size_t)i * 512 + dt * 128 + dl];
        #pragma unroll
        for (int j = 0; j < 8; j++) acc[j] += ztT[i][gq * 8 + j] * m;
    }
    #pragma unroll
    for (int j = 0; j < 8; j++) {
        int g = gq * 8 + j;
        part2[((size_t)cc * 32 + g) * 512 + dt * 128 + dl] = acc[j];
    }
}

// ---------------------------------------------------------------------------
// K2b: h0 reduce + relu + pack bf16 pairs.  h0t[g*256 + p] = bf16(2p)|bf16(2p+1)<<16
// ---------------------------------------------------------------------------
__device__ __forceinline__ unsigned bf16rne(float f) {
    unsigned u = __float_as_uint(f);
    return (u + 0x7FFFu + ((u >> 16) & 1u)) >> 16;
}

__global__ __launch_bounds__(256) void k_h0(const float* __restrict__ part2,
                                            const float* __restrict__ bias_conv,
                                            unsigned* __restrict__ h0t) {
    int g = blockIdx.x;
    int p = threadIdx.x;
    int d0 = 2 * p;
    float v0 = bias_conv[d0], v1 = bias_conv[d0 + 1];
    for (int cc = 0; cc < NCH; cc++) {
        const float* pp = part2 + ((size_t)cc * 32 + g) * 512 + d0;
        v0 += pp[0];
        v1 += pp[1];
    }
    v0 = fmaxf(v0, 0.f);
    v1 = fmaxf(v1, 0.f);
    h0t[g * 256 + p] = bf16rne(v0) | (bf16rne(v1) << 16);
}

// ---------------------------------------------------------------------------
// K3 v10 = R7's best-measured structure + fused log-softmax partials.
// 586 blocks x 8 waves; each wave owns one 16-row x K=512 W tile (32KB),
// rolling 4-deep register prefetch, PLAIN loads (no NT: keep L3 retention of
// W across graph replays), no barriers after the single h0 staging sync.
// Epilogue: logits store + per-tile exp-partials -> part[tile*32+g]
// (replaces the 9.6MB k_lse_part re-read pass).
// ---------------------------------------------------------------------------
__device__ __forceinline__ short f2bf(float f) {
    __hip_bfloat16 h = __float2bfloat16(f);
    return *reinterpret_cast<short*>(&h);
}

__global__ __launch_bounds__(512, 4) void k_logits10(const unsigned* __restrict__ h0t,
                                                     const float* __restrict__ wg,
                                                     const float* __restrict__ bg,
                                                     const float* __restrict__ wsn,
                                                     const float* __restrict__ bsv,
                                                     float* __restrict__ out,
                                                     float* __restrict__ part) {
    __shared__ __align__(16) unsigned char hlds[32768];   // h0 [32 g][1KB], 16B-XOR

    int t = threadIdx.x;          // 0..511
    int wv = t >> 6, l = t & 63;

    // ---- h0 -> LDS (16B-granule XOR by batch row); once per block ----
    #pragma unroll
    for (int rep = 0; rep < 4; rep++) {
        int idx = rep * 512 + t;               // uint4 index, 2048 total
        int g = idx >> 6, q = idx & 63;
        uint4 val = *(const uint4*)&h0t[idx * 4];
        *(uint4*)&hlds[g * 1024 + ((q ^ (g & 7)) << 4)] = val;
    }
    __syncthreads();

    // ---- wave-private tile ----
    int tile = blockIdx.x * 8 + wv;            // 0..4687
    const float* w; const float* bias; float* ob; int V; int v0;
    if (tile < NT_G) { w = wg;  bias = bg;  ob = out;                      V = VG; v0 = tile * 16; }
    else             { w = wsn; bias = bsv; ob = out + (size_t)BATCH * VG; V = VS; v0 = (tile - NT_G) * 16; }

    int c  = l & 15;          // vocab col within tile AND h0 batch row
    int kg = l >> 4;          // k-quarter 0..3
    int vb = v0 + c;
    int vr = (vb < V) ? vb : (V - 1);
    const f32x4* __restrict__ wrow = (const f32x4*)(w + (size_t)vr * 512) + kg * 2;
    int swz = c & 7;
    const unsigned char* ha = &hlds[c * 1024];
    const unsigned char* hb = &hlds[(c + 16) * 1024];

    // ---- rolling 4-deep prefetch into registers ----
    f32x4 wb[4][2];
    #pragma unroll
    for (int p = 0; p < 4; p++) {
        wb[p][0] = wrow[p * 8];
        wb[p][1] = wrow[p * 8 + 1];
    }

    f32x4 acc0 = {0.f, 0.f, 0.f, 0.f};
    f32x4 acc1 = {0.f, 0.f, 0.f, 0.f};

    #pragma unroll
    for (int kc = 0; kc < 16; kc++) {
        f32x4 b0 = wb[kc & 3][0];
        f32x4 b1 = wb[kc & 3][1];
        if (kc + 4 < 16) {
            wb[kc & 3][0] = wrow[(kc + 4) * 8];
            wb[kc & 3][1] = wrow[(kc + 4) * 8 + 1];
        }
        int gr = ((kc * 4 + kg) ^ swz) << 4;
        s16x8 a0 = *(const s16x8*)(ha + gr);
        s16x8 a1 = *(const s16x8*)(hb + gr);
        s16x8 bf;
        bf[0] = f2bf(b0[0]); bf[1] = f2bf(b0[1]); bf[2] = f2bf(b0[2]); bf[3] = f2bf(b0[3]);
        bf[4] = f2bf(b1[0]); bf[5] = f2bf(b1[1]); bf[6] = f2bf(b1[2]); bf[7] = f2bf(b1[3]);
        acc0 = __builtin_amdgcn_mfma_f32_16x16x32_bf16(a0, bf, acc0, 0, 0, 0);
        acc1 = __builtin_amdgcn_mfma_f32_16x16x32_bf16(a1, bf, acc1, 0, 0, 0);
    }

    // ---- epilogue: C/D layout col=lane&15 (vocab), row=(lane>>4)*4+j (batch) ----
    float p0[4], p1[4];
    bool valid = (vb < V);
    float bia = valid ? bias[vb] : 0.f;
    #pragma unroll
    for (int j = 0; j < 4; j++) {
        float v0f = acc0[j] + bia;
        float v1f = acc1[j] + bia;
        int g0 = kg * 4 + j;
        if (valid) {
            ob[(size_t)g0 * V + vb]        = v0f;
            ob[(size_t)(g0 + 16) * V + vb] = v1f;
        }
        p0[j] = valid ? __expf(v0f) : 0.f;
        p1[j] = valid ? __expf(v1f) : 0.f;
    }
    // butterfly over the 16 c-lanes of this kg-group (lane bits 0..3)
    #pragma unroll
    for (int s = 1; s < 16; s <<= 1) {
        #pragma unroll
        for (int j = 0; j < 4; j++) {
            p0[j] += __shfl_xor(p0[j], s);
            p1[j] += __shfl_xor(p1[j], s);
        }
    }
    if (c == 0) {
        float* pt = part + (size_t)tile * 32;
        #pragma unroll
        for (int j = 0; j < 4; j++) {
            pt[kg * 4 + j]      = p0[j];
            pt[kg * 4 + j + 16] = p1[j];
        }
    }
}

// ---------------------------------------------------------------------------
// K4a: lse[row] = log(sum over tiles of part[tile*32+g]); row = head*32+g
// ---------------------------------------------------------------------------
__global__ __launch_bounds__(256) void k_lse64(const float* __restrict__ part,
                                               float* __restrict__ lse) {
    int bx = blockIdx.x;           // 0..63
    int head = bx >> 5, g = bx & 31;
    int tbase = head ? NT_G : 0;
    int ntl   = head ? (TTOT - NT_G) : NT_G;
    int t = threadIdx.x;
    float s = 0.f;
    for (int i = t; i < ntl; i += 256)
        s += part[(size_t)(tbase + i) * 32 + g];
    #pragma unroll
    for (int m = 1; m < 64; m <<= 1) s += __shfl_xor(s, m);
    __shared__ float ws4[4];
    if ((t & 63) == 0) ws4[t >> 6] = s;
    __syncthreads();
    if (t == 0) lse[bx] = logf(ws4[0] + ws4[1] + ws4[2] + ws4[3]);
}

// ---------------------------------------------------------------------------
// K4b: out -= lse (broadcast per row)
// ---------------------------------------------------------------------------
__global__ __launch_bounds__(256) void k_sub(float* __restrict__ out,
                                             const float* __restrict__ lse) {
    unsigned i4 = blockIdx.x * 256u + threadIdx.x;
    if (i4 >= 600000u) return;
    unsigned idx = i4 * 4u;
    float l;
    if (idx < 1600000u) l = lse[idx / 50000u];
    else                l = lse[32u + (idx - 1600000u) / 25000u];
    float4 v = *(float4*)(out + idx);
    v.x -= l; v.y -= l; v.z -= l; v.w -= l;
    *(float4*)(out + idx) = v;
}

// ---------------------------------------------------------------------------
extern "C" void kernel_launch(void* const* d_in, const int* in_sizes, int n_in,
                              void* d_out, int out_size, void* d_ws, size_t ws_size,
                              hipStream_t stream) {
    const float* x        = (const float*)d_in[0];
    const int*   ei       = (const int*)  d_in[1];
    const int*   et       = (const int*)  d_in[2];
    const float* basis    = (const float*)d_in[3];
    const float* comp     = (const float*)d_in[4];
    const float* root     = (const float*)d_in[5];
    const float* biasc    = (const float*)d_in[6];
    const float* wg       = (const float*)d_in[7];
    const float* bg       = (const float*)d_in[8];
    const float* wsn      = (const float*)d_in[9];
    const float* bsv      = (const float*)d_in[10];
    float* out = (float*)d_out;

    float* z     = out;
    float* part2 = out + (size_t)BATCH * ZI;
    unsigned* h0t  = (unsigned*)d_ws;            // 8192 uints = 32KB
    float*    part = (float*)d_ws + 8192;        // 4688*32 floats = 600KB
    float*    lse  = part + (size_t)TTOT * 32;   // 64 floats

    k_conv      <<<BATCH, 512, 0, stream>>>(x, ei, et, comp, z);
    k_gemm_part <<<NCH * 4, 512, 0, stream>>>(z, root, basis, part2);
    k_h0        <<<BATCH, 256, 0, stream>>>(part2, biasc, h0t);
    k_logits10  <<<NBLKA, 512, 0, stream>>>(h0t, wg, bg, wsn, bsv, out, part);
    k_lse64     <<<64, 256, 0, stream>>>(part, lse);
    k_sub       <<<2344, 256, 0, stream>>>(out, lse);
}